// Round 1
// baseline (3520.125 us; speedup 1.0000x reference)
//
#include <hip/hip_runtime.h>

#define N_NODES 100000
#define E_EDGES 3200000

// ---------------------------------------------------------------------------
// ws layout (float offsets):
//   hem   [0,        6400000)   N*64   h_em = x @ emb_w + emb_b
//   s8    [6400000,  7200000)   N*8    [s_src(4) | s_dst(4)] per node
//   Wa    [7200000,  7202048)   256*8  fused W_lin @ [a_src|a_dst]^T
//   off8  [7202048,  7202056)   8      b_lin . a^T
//   denom [7202056,  7602056)   N*4    segment sums of w
// total ~30.4 MB
// ---------------------------------------------------------------------------

__global__ void fuse_weights_kernel(const float* __restrict__ W_lin,
                                    const float* __restrict__ b_lin,
                                    const float* __restrict__ att_w,
                                    float* __restrict__ Wa,
                                    float* __restrict__ off8) {
    int k = threadIdx.x;  // 0..255, one row of W_lin
    float acc[8];
#pragma unroll
    for (int j = 0; j < 8; ++j) acc[j] = 0.f;
    for (int c = 0; c < 256; ++c) {
        float w = W_lin[k * 256 + c];
#pragma unroll
        for (int l = 0; l < 4; ++l) {
            acc[l]     += w * att_w[l * 512 + c];        // a_src[l][c]
            acc[4 + l] += w * att_w[l * 512 + 256 + c];  // a_dst[l][c]
        }
    }
#pragma unroll
    for (int j = 0; j < 8; ++j) Wa[k * 8 + j] = acc[j];
    if (k < 8) {
        int l = k & 3, part = k >> 2;
        float o = 0.f;
        for (int c = 0; c < 256; ++c)
            o += b_lin[c] * att_w[l * 512 + part * 256 + c];
        off8[k] = o;
    }
}

// One wave per node row: h_em[row][0..63] and s8[row][0..7]
__global__ __launch_bounds__(256) void row_kernel(
    const float* __restrict__ x,
    const float* __restrict__ emb_w, const float* __restrict__ emb_b,
    const float* __restrict__ Wa, const float* __restrict__ off8,
    float* __restrict__ hem, float* __restrict__ s8) {
    __shared__ float xs[4][256];
    const int wave = threadIdx.x >> 6, lane = threadIdx.x & 63;
    const int gw = blockIdx.x * 4 + wave, nw = gridDim.x * 4;
    const float eb = emb_b[lane];
    for (int row = gw; row < N_NODES; row += nw) {
        float4 xv = *(const float4*)(x + (size_t)row * 256 + lane * 4);
        *(float4*)(&xs[wave][lane * 4]) = xv;
        // same-wave DS ops are in-order; per-wave buffer so no block barrier

        // s8 partials over this lane's 4 k-values (statically indexed)
        const float* wak = Wa + (lane * 4) * 8;
        float sp[8];
#pragma unroll
        for (int j = 0; j < 8; ++j)
            sp[j] = xv.x * wak[j] + xv.y * wak[8 + j] +
                    xv.z * wak[16 + j] + xv.w * wak[24 + j];

        // h_em: lane owns column `lane`
        float acc = eb;
        for (int k = 0; k < 256; ++k)
            acc += xs[wave][k] * emb_w[k * 64 + lane];
        hem[(size_t)row * 64 + lane] = acc;

        // wave-reduce the 8 s-partials
#pragma unroll
        for (int j = 0; j < 8; ++j) {
            float v = sp[j];
#pragma unroll
            for (int off = 32; off >= 1; off >>= 1) v += __shfl_xor(v, off);
            sp[j] = v;
        }
        if (lane == 0) {
#pragma unroll
            for (int j = 0; j < 8; ++j)
                s8[(size_t)row * 8 + j] = sp[j] + off8[j];
        }
    }
}

// One wave per edge (grid-stride): scatter w_l * h_em[dst] into out[src]
__global__ __launch_bounds__(256) void edge_kernel(
    const int* __restrict__ src, const int* __restrict__ dst,
    const float* __restrict__ s8, const float* __restrict__ att_b,
    const float* __restrict__ hem,
    float* __restrict__ out, float* __restrict__ denom) {
    const int lane = threadIdx.x & 63;
    const int gw = (blockIdx.x * blockDim.x + threadIdx.x) >> 6;
    const int nw = (gridDim.x * blockDim.x) >> 6;
    for (int e = gw; e < E_EDGES; e += nw) {
        int s = src[e], d = dst[e];
        float hd = hem[(size_t)d * 64 + lane];
        const float* ss = s8 + (size_t)s * 8;
        const float* sd = s8 + (size_t)d * 8 + 4;
#pragma unroll
        for (int l = 0; l < 4; ++l) {
            float t = ss[l] + sd[l] + att_b[l];
            float sg = 1.f / (1.f + __expf(-t));
            float wl = __expf(sg);   // global max cancels in attn ratio
            atomicAdd(&out[(size_t)s * 256 + l * 64 + lane], wl * hd);
            if (lane == l) atomicAdd(&denom[(size_t)s * 4 + l], wl);
        }
    }
}

__global__ __launch_bounds__(256) void finalize_kernel(
    float* __restrict__ out, const float* __restrict__ denom) {
    int i = blockIdx.x * 256 + threadIdx.x;  // exactly N*256 threads
    int n = i >> 8;
    int l = (i >> 6) & 3;
    float dn = denom[n * 4 + l];
    float v = out[i];
    out[i] = dn > 0.f ? v / dn : 0.f;
}

extern "C" void kernel_launch(void* const* d_in, const int* in_sizes, int n_in,
                              void* d_out, int out_size, void* d_ws, size_t ws_size,
                              hipStream_t stream) {
    const float* x     = (const float*)d_in[0];
    const int*   src   = (const int*)d_in[1];
    const int*   dst   = (const int*)d_in[2];
    const float* W_lin = (const float*)d_in[3];
    const float* b_lin = (const float*)d_in[4];
    const float* att_w = (const float*)d_in[5];
    const float* att_b = (const float*)d_in[6];
    const float* emb_w = (const float*)d_in[7];
    const float* emb_b = (const float*)d_in[8];
    float* out = (float*)d_out;
    float* ws  = (float*)d_ws;

    float* hem   = ws;
    float* s8    = ws + 6400000;
    float* Wa    = ws + 7200000;
    float* off8  = ws + 7202048;
    float* denom = ws + 7202056;

    hipMemsetAsync(d_out, 0, (size_t)N_NODES * 256 * sizeof(float), stream);
    hipMemsetAsync(denom, 0, (size_t)N_NODES * 4 * sizeof(float), stream);

    fuse_weights_kernel<<<1, 256, 0, stream>>>(W_lin, b_lin, att_w, Wa, off8);
    row_kernel<<<2048, 256, 0, stream>>>(x, emb_w, emb_b, Wa, off8, hem, s8);
    edge_kernel<<<4096, 256, 0, stream>>>(src, dst, s8, att_b, hem, out, denom);
    finalize_kernel<<<N_NODES, 256, 0, stream>>>(out, denom);
}

// Round 2
// 1220.083 us; speedup vs baseline: 2.8852x; 2.8852x over previous
//
#include <hip/hip_runtime.h>

#define N_NODES 100000
#define E_EDGES 3200000

// ---------------------------------------------------------------------------
// ws layout (float offsets):
//   hem    [0,        6400000)    N*64   h_em = x @ emb_w + emb_b
//   s8     [6400000,  7200000)    N*8    [s_src+att_b (4) | s_dst (4)] per node
//   Wa     [7200000,  7202048)    256*8  fused W_lin @ [a_src|a_dst]^T
//   off8   [7202048,  7202056)    8      b_lin . a^T
//   counts [7202056,  7302056)    N ints
//   rowptr [7302056,  7402057)    N+1 ints
//   fill   [7402064,  7502064)    N ints
//   sdst   [7502064, 10702064)    E ints (dst sorted by src)
// total ~42.8 MB
// ---------------------------------------------------------------------------

__global__ void fuse_weights_kernel(const float* __restrict__ W_lin,
                                    const float* __restrict__ b_lin,
                                    const float* __restrict__ att_w,
                                    float* __restrict__ Wa,
                                    float* __restrict__ off8) {
    int k = threadIdx.x;  // 0..255, one row of W_lin
    float acc[8];
#pragma unroll
    for (int j = 0; j < 8; ++j) acc[j] = 0.f;
    for (int c = 0; c < 256; ++c) {
        float w = W_lin[k * 256 + c];
#pragma unroll
        for (int l = 0; l < 4; ++l) {
            acc[l]     += w * att_w[l * 512 + c];        // a_src[l][c]
            acc[4 + l] += w * att_w[l * 512 + 256 + c];  // a_dst[l][c]
        }
    }
#pragma unroll
    for (int j = 0; j < 8; ++j) Wa[k * 8 + j] = acc[j];
    if (k < 8) {
        int l = k & 3, part = k >> 2;
        float o = 0.f;
        for (int c = 0; c < 256; ++c)
            o += b_lin[c] * att_w[l * 512 + part * 256 + c];
        off8[k] = o;
    }
}

// One wave per node row: h_em[row][0..63] and s8[row][0..7] (att_b folded
// into the src half so the edge kernel needs one add per head).
__global__ __launch_bounds__(256) void row_kernel(
    const float* __restrict__ x,
    const float* __restrict__ emb_w, const float* __restrict__ emb_b,
    const float* __restrict__ Wa, const float* __restrict__ off8,
    const float* __restrict__ att_b,
    float* __restrict__ hem, float* __restrict__ s8) {
    __shared__ float xs[4][256];
    const int wave = threadIdx.x >> 6, lane = threadIdx.x & 63;
    const int gw = blockIdx.x * 4 + wave, nw = gridDim.x * 4;
    const float eb = emb_b[lane];
    for (int row = gw; row < N_NODES; row += nw) {
        float4 xv = *(const float4*)(x + (size_t)row * 256 + lane * 4);
        *(float4*)(&xs[wave][lane * 4]) = xv;
        // same-wave DS ops are in-order; per-wave buffer so no block barrier

        const float* wak = Wa + (lane * 4) * 8;
        float sp[8];
#pragma unroll
        for (int j = 0; j < 8; ++j)
            sp[j] = xv.x * wak[j] + xv.y * wak[8 + j] +
                    xv.z * wak[16 + j] + xv.w * wak[24 + j];

        float acc = eb;
        for (int k = 0; k < 256; ++k)
            acc += xs[wave][k] * emb_w[k * 64 + lane];
        hem[(size_t)row * 64 + lane] = acc;

#pragma unroll
        for (int j = 0; j < 8; ++j) {
            float v = sp[j];
#pragma unroll
            for (int off = 32; off >= 1; off >>= 1) v += __shfl_xor(v, off);
            sp[j] = v;
        }
        if (lane == 0) {
#pragma unroll
            for (int j = 0; j < 8; ++j) {
                float extra = (j < 4) ? att_b[j] : 0.f;
                s8[(size_t)row * 8 + j] = sp[j] + off8[j] + extra;
            }
        }
    }
}

__global__ __launch_bounds__(256) void hist_kernel(const int* __restrict__ src,
                                                   int* __restrict__ counts) {
    int i = blockIdx.x * blockDim.x + threadIdx.x;
    int stride = gridDim.x * blockDim.x;
    for (int e = i; e < E_EDGES; e += stride)
        atomicAdd(&counts[src[e]], 1);
}

// Single-block exclusive scan over N counts -> rowptr[N+1]
__global__ __launch_bounds__(256) void scan_kernel(const int* __restrict__ counts,
                                                   int* __restrict__ rowptr) {
    __shared__ int sums[256];
    const int t = threadIdx.x;
    const int chunk = (N_NODES + 255) / 256;  // 391
    const int beg = t * chunk;
    const int end = min(beg + chunk, N_NODES);
    int s = 0;
    for (int i = beg; i < end; ++i) s += counts[i];
    sums[t] = s;
    __syncthreads();
    for (int off = 1; off < 256; off <<= 1) {
        int v = (t >= off) ? sums[t - off] : 0;
        __syncthreads();
        sums[t] += v;
        __syncthreads();
    }
    int pre = (t == 0) ? 0 : sums[t - 1];
    for (int i = beg; i < end; ++i) {
        rowptr[i] = pre;
        pre += counts[i];
    }
    if (t == 255) rowptr[N_NODES] = pre;
}

__global__ __launch_bounds__(256) void scatter_kernel(
    const int* __restrict__ src, const int* __restrict__ dst,
    const int* __restrict__ rowptr, int* __restrict__ fill,
    int* __restrict__ sdst) {
    int i = blockIdx.x * blockDim.x + threadIdx.x;
    int stride = gridDim.x * blockDim.x;
    for (int e = i; e < E_EDGES; e += stride) {
        int s = src[e];
        int pos = rowptr[s] + atomicAdd(&fill[s], 1);
        sdst[pos] = dst[e];
    }
}

__device__ __forceinline__ void edge_acc(const float4& ssv, const float4& sdv,
                                         float hd, float* acc, float* den) {
    float t0 = ssv.x + sdv.x, t1 = ssv.y + sdv.y;
    float t2 = ssv.z + sdv.z, t3 = ssv.w + sdv.w;
    float w0 = __expf(1.f / (1.f + __expf(-t0)));
    float w1 = __expf(1.f / (1.f + __expf(-t1)));
    float w2 = __expf(1.f / (1.f + __expf(-t2)));
    float w3 = __expf(1.f / (1.f + __expf(-t3)));
    acc[0] += w0 * hd; den[0] += w0;
    acc[1] += w1 * hd; den[1] += w1;
    acc[2] += w2 * hd; den[2] += w2;
    acc[3] += w3 * hd; den[3] += w3;
}

// One wave per src node: register-accumulate the 256-wide output row.
__global__ __launch_bounds__(256) void node_kernel(
    const int* __restrict__ rowptr, const int* __restrict__ sdst,
    const float* __restrict__ s8, const float* __restrict__ hem,
    float* __restrict__ out) {
    const int lane = threadIdx.x & 63;
    const int gw = (blockIdx.x * blockDim.x + threadIdx.x) >> 6;
    const int nw = (gridDim.x * blockDim.x) >> 6;
    for (int s = gw; s < N_NODES; s += nw) {
        const int beg = rowptr[s], end = rowptr[s + 1];
        const float4 ssv = *(const float4*)(s8 + (size_t)s * 8);  // att_b folded
        float acc[4] = {0.f, 0.f, 0.f, 0.f};
        float den[4] = {0.f, 0.f, 0.f, 0.f};
        int j = beg;
        for (; j + 1 < end; j += 2) {  // unroll-2 for memory-level parallelism
            int d0 = sdst[j], d1 = sdst[j + 1];
            float4 sd0 = *(const float4*)(s8 + (size_t)d0 * 8 + 4);
            float4 sd1 = *(const float4*)(s8 + (size_t)d1 * 8 + 4);
            float h0 = hem[(size_t)d0 * 64 + lane];
            float h1 = hem[(size_t)d1 * 64 + lane];
            edge_acc(ssv, sd0, h0, acc, den);
            edge_acc(ssv, sd1, h1, acc, den);
        }
        if (j < end) {
            int d0 = sdst[j];
            float4 sd0 = *(const float4*)(s8 + (size_t)d0 * 8 + 4);
            float h0 = hem[(size_t)d0 * 64 + lane];
            edge_acc(ssv, sd0, h0, acc, den);
        }
#pragma unroll
        for (int l = 0; l < 4; ++l)
            out[(size_t)s * 256 + l * 64 + lane] =
                den[l] > 0.f ? acc[l] / den[l] : 0.f;
    }
}

extern "C" void kernel_launch(void* const* d_in, const int* in_sizes, int n_in,
                              void* d_out, int out_size, void* d_ws, size_t ws_size,
                              hipStream_t stream) {
    const float* x     = (const float*)d_in[0];
    const int*   src   = (const int*)d_in[1];
    const int*   dst   = (const int*)d_in[2];
    const float* W_lin = (const float*)d_in[3];
    const float* b_lin = (const float*)d_in[4];
    const float* att_w = (const float*)d_in[5];
    const float* att_b = (const float*)d_in[6];
    const float* emb_w = (const float*)d_in[7];
    const float* emb_b = (const float*)d_in[8];
    float* out = (float*)d_out;
    float* ws  = (float*)d_ws;

    float* hem   = ws;
    float* s8    = ws + 6400000;
    float* Wa    = ws + 7200000;
    float* off8  = ws + 7202048;
    int*   counts = (int*)(ws + 7202056);
    int*   rowptr = (int*)(ws + 7302056);
    int*   fill   = (int*)(ws + 7402064);
    int*   sdst   = (int*)(ws + 7502064);

    hipMemsetAsync(counts, 0, N_NODES * sizeof(int), stream);
    hipMemsetAsync(fill, 0, N_NODES * sizeof(int), stream);

    fuse_weights_kernel<<<1, 256, 0, stream>>>(W_lin, b_lin, att_w, Wa, off8);
    row_kernel<<<2048, 256, 0, stream>>>(x, emb_w, emb_b, Wa, off8, att_b,
                                         hem, s8);
    hist_kernel<<<2048, 256, 0, stream>>>(src, counts);
    scan_kernel<<<1, 256, 0, stream>>>(counts, rowptr);
    scatter_kernel<<<2048, 256, 0, stream>>>(src, dst, rowptr, fill, sdst);
    node_kernel<<<4096, 256, 0, stream>>>(rowptr, sdst, s8, hem, out);
}

// Round 3
// 851.698 us; speedup vs baseline: 4.1331x; 1.4325x over previous
//
#include <hip/hip_runtime.h>

#define N_NODES 100000
#define E_EDGES 3200000

// ---------------------------------------------------------------------------
// ws layout (float offsets):
//   hem    [0,        6400000)    N*64   h_em = x @ emb_w + emb_b
//   s8     [6400000,  7200000)    N*8    [s_src+att_b (4) | s_dst (4)] per node
//   Wa     [7200000,  7202048)    256*8  fused W_lin @ [a_src|a_dst]^T
//   off8   [7202048,  7202056)    8      b_lin . a^T
//   counts [7202056,  7302056)    N ints (zeroed by scan, reused as fill)
//   rowptr [7302056,  7402057)    N+1 ints
//   sdst   [7502064, 10702064)    E ints (dst sorted by src)
// ---------------------------------------------------------------------------

__global__ void fuse_weights_kernel(const float* __restrict__ W_lin,
                                    const float* __restrict__ b_lin,
                                    const float* __restrict__ att_w,
                                    float* __restrict__ Wa,
                                    float* __restrict__ off8) {
    int k = threadIdx.x;  // 0..255, one row of W_lin
    float acc[8];
#pragma unroll
    for (int j = 0; j < 8; ++j) acc[j] = 0.f;
    for (int c = 0; c < 256; ++c) {
        float w = W_lin[k * 256 + c];
#pragma unroll
        for (int l = 0; l < 4; ++l) {
            acc[l]     += w * att_w[l * 512 + c];        // a_src[l][c]
            acc[4 + l] += w * att_w[l * 512 + 256 + c];  // a_dst[l][c]
        }
    }
#pragma unroll
    for (int j = 0; j < 8; ++j) Wa[k * 8 + j] = acc[j];
    if (k < 8) {
        int l = k & 3, part = k >> 2;
        float o = 0.f;
        for (int c = 0; c < 256; ++c)
            o += b_lin[c] * att_w[l * 512 + part * 256 + c];
        off8[k] = o;
    }
}

// 4 rows per wave: hem[row][0..63] for 4 rows (emb_w reuse x4) + s8 rows.
__global__ __launch_bounds__(256) void row_kernel(
    const float* __restrict__ x,
    const float* __restrict__ emb_w, const float* __restrict__ emb_b,
    const float* __restrict__ Wa, const float* __restrict__ off8,
    const float* __restrict__ att_b,
    float* __restrict__ hem, float* __restrict__ s8) {
    __shared__ float4 xs4[4][4][64];  // [wave][row][k/4] = 16 KB
    const int wave = threadIdx.x >> 6, lane = threadIdx.x & 63;
    const int gw = blockIdx.x * 4 + wave, nw = gridDim.x * 4;
    const float eb = emb_b[lane];
    const float* wak = Wa + (lane * 4) * 8;
    for (int g = gw; g < N_NODES / 4; g += nw) {  // 25000 full groups
        const int row0 = g * 4;
        float4 xv[4];
#pragma unroll
        for (int r = 0; r < 4; ++r) {
            xv[r] = *(const float4*)(x + (size_t)(row0 + r) * 256 + lane * 4);
            xs4[wave][r][lane] = xv[r];
        }
        // s8 for each of the 4 rows (from registers, wave shuffle-reduce)
#pragma unroll
        for (int r = 0; r < 4; ++r) {
            float sp[8];
#pragma unroll
            for (int j = 0; j < 8; ++j)
                sp[j] = xv[r].x * wak[j] + xv[r].y * wak[8 + j] +
                        xv[r].z * wak[16 + j] + xv[r].w * wak[24 + j];
#pragma unroll
            for (int j = 0; j < 8; ++j) {
                float v = sp[j];
#pragma unroll
                for (int off = 32; off >= 1; off >>= 1) v += __shfl_xor(v, off);
                sp[j] = v;
            }
            if (lane == 0) {
#pragma unroll
                for (int j = 0; j < 8; ++j) {
                    float extra = (j < 4) ? att_b[j] : 0.f;
                    s8[(size_t)(row0 + r) * 8 + j] = sp[j] + off8[j] + extra;
                }
            }
        }
        // hem: lane owns column `lane`; emb_w value reused across 4 rows
        float ac0 = eb, ac1 = eb, ac2 = eb, ac3 = eb;
        for (int k4 = 0; k4 < 64; ++k4) {
            float4 x0 = xs4[wave][0][k4], x1 = xs4[wave][1][k4];
            float4 x2 = xs4[wave][2][k4], x3 = xs4[wave][3][k4];
            const float* ew = emb_w + (size_t)k4 * 256 + lane;
            float w0 = ew[0], w1 = ew[64], w2 = ew[128], w3 = ew[192];
            ac0 += x0.x * w0 + x0.y * w1 + x0.z * w2 + x0.w * w3;
            ac1 += x1.x * w0 + x1.y * w1 + x1.z * w2 + x1.w * w3;
            ac2 += x2.x * w0 + x2.y * w1 + x2.z * w2 + x2.w * w3;
            ac3 += x3.x * w0 + x3.y * w1 + x3.z * w2 + x3.w * w3;
        }
        hem[(size_t)(row0 + 0) * 64 + lane] = ac0;
        hem[(size_t)(row0 + 1) * 64 + lane] = ac1;
        hem[(size_t)(row0 + 2) * 64 + lane] = ac2;
        hem[(size_t)(row0 + 3) * 64 + lane] = ac3;
    }
}

__global__ __launch_bounds__(256) void hist_kernel(const int* __restrict__ src,
                                                   int* __restrict__ counts) {
    int i = blockIdx.x * blockDim.x + threadIdx.x;
    int stride = gridDim.x * blockDim.x;
    for (int e = i; e < E_EDGES; e += stride)
        atomicAdd(&counts[src[e]], 1);
}

// Single-block exclusive scan; also zeroes counts so scatter can reuse it.
__global__ __launch_bounds__(1024) void scan_kernel(int* __restrict__ counts,
                                                    int* __restrict__ rowptr) {
    __shared__ int sums[1024];
    const int t = threadIdx.x;
    const int chunk = (N_NODES + 1023) / 1024;  // 98
    const int beg = t * chunk;
    const int end = min(beg + chunk, N_NODES);
    int s = 0;
    for (int i = beg; i < end; ++i) s += counts[i];
    sums[t] = s;
    __syncthreads();
    for (int off = 1; off < 1024; off <<= 1) {
        int v = (t >= off) ? sums[t - off] : 0;
        __syncthreads();
        sums[t] += v;
        __syncthreads();
    }
    int pre = (t == 0) ? 0 : sums[t - 1];
    for (int i = beg; i < end; ++i) {
        rowptr[i] = pre;
        pre += counts[i];
        counts[i] = 0;  // becomes the fill array for scatter
    }
    if (t == 1023) rowptr[N_NODES] = pre;
}

__global__ __launch_bounds__(256) void scatter_kernel(
    const int* __restrict__ src, const int* __restrict__ dst,
    const int* __restrict__ rowptr, int* __restrict__ fill,
    int* __restrict__ sdst) {
    int i = blockIdx.x * blockDim.x + threadIdx.x;
    int stride = gridDim.x * blockDim.x;
    for (int e = i; e < E_EDGES; e += stride) {
        int s = src[e];
        int pos = rowptr[s] + atomicAdd(&fill[s], 1);
        sdst[pos] = dst[e];
    }
}

// One wave per src node. Phase 1: each lane computes the 4 edge-weights for
// ONE edge of the batch (64x fewer transcendentals than r2) -> LDS. Phase 2:
// broadcast-read the weights, gather hem rows, accumulate in registers.
__global__ __launch_bounds__(256) void node_kernel(
    const int* __restrict__ rowptr, const int* __restrict__ sdst,
    const float* __restrict__ s8, const float* __restrict__ hem,
    float* __restrict__ out) {
    __shared__ int    wd[4][64];
    __shared__ float4 ww[4][64];
    const int wave = threadIdx.x >> 6, lane = threadIdx.x & 63;
    const int gw = (blockIdx.x * blockDim.x + threadIdx.x) >> 6;
    const int nw = (gridDim.x * blockDim.x) >> 6;
    for (int s = gw; s < N_NODES; s += nw) {
        const int beg = rowptr[s], end = rowptr[s + 1];
        const float4 ssv = *(const float4*)(s8 + (size_t)s * 8);  // +att_b
        float a0 = 0.f, a1 = 0.f, a2 = 0.f, a3 = 0.f;
        float d0 = 0.f, d1 = 0.f, d2 = 0.f, d3 = 0.f;
        for (int base = beg; base < end; base += 64) {
            const int m = min(64, end - base);
            if (lane < m) {
                int dj = sdst[base + lane];
                float4 sd = *(const float4*)(s8 + (size_t)dj * 8 + 4);
                float w0 = __expf(1.f / (1.f + __expf(-(ssv.x + sd.x))));
                float w1 = __expf(1.f / (1.f + __expf(-(ssv.y + sd.y))));
                float w2 = __expf(1.f / (1.f + __expf(-(ssv.z + sd.z))));
                float w3 = __expf(1.f / (1.f + __expf(-(ssv.w + sd.w))));
                wd[wave][lane] = dj;
                ww[wave][lane] = make_float4(w0, w1, w2, w3);
            }
            // producer and consumer are the same wave: DS ops are in-order,
            // no block barrier needed (per-wave LDS buffers).
            int j = 0;
            for (; j + 1 < m; j += 2) {
                int da = wd[wave][j], db = wd[wave][j + 1];
                float4 wa = ww[wave][j], wb = ww[wave][j + 1];
                float ha = hem[(size_t)da * 64 + lane];
                float hb = hem[(size_t)db * 64 + lane];
                a0 += wa.x * ha; a1 += wa.y * ha; a2 += wa.z * ha; a3 += wa.w * ha;
                d0 += wa.x + wb.x; d1 += wa.y + wb.y;
                d2 += wa.z + wb.z; d3 += wa.w + wb.w;
                a0 += wb.x * hb; a1 += wb.y * hb; a2 += wb.z * hb; a3 += wb.w * hb;
            }
            if (j < m) {
                int da = wd[wave][j];
                float4 wa = ww[wave][j];
                float ha = hem[(size_t)da * 64 + lane];
                a0 += wa.x * ha; a1 += wa.y * ha; a2 += wa.z * ha; a3 += wa.w * ha;
                d0 += wa.x; d1 += wa.y; d2 += wa.z; d3 += wa.w;
            }
        }
        float* o = out + (size_t)s * 256;
        o[lane]       = d0 > 0.f ? a0 / d0 : 0.f;
        o[64 + lane]  = d1 > 0.f ? a1 / d1 : 0.f;
        o[128 + lane] = d2 > 0.f ? a2 / d2 : 0.f;
        o[192 + lane] = d3 > 0.f ? a3 / d3 : 0.f;
    }
}

extern "C" void kernel_launch(void* const* d_in, const int* in_sizes, int n_in,
                              void* d_out, int out_size, void* d_ws, size_t ws_size,
                              hipStream_t stream) {
    const float* x     = (const float*)d_in[0];
    const int*   src   = (const int*)d_in[1];
    const int*   dst   = (const int*)d_in[2];
    const float* W_lin = (const float*)d_in[3];
    const float* b_lin = (const float*)d_in[4];
    const float* att_w = (const float*)d_in[5];
    const float* att_b = (const float*)d_in[6];
    const float* emb_w = (const float*)d_in[7];
    const float* emb_b = (const float*)d_in[8];
    float* out = (float*)d_out;
    float* ws  = (float*)d_ws;

    float* hem    = ws;
    float* s8     = ws + 6400000;
    float* Wa     = ws + 7200000;
    float* off8   = ws + 7202048;
    int*   counts = (int*)(ws + 7202056);
    int*   rowptr = (int*)(ws + 7302056);
    int*   sdst   = (int*)(ws + 7502064);

    hipMemsetAsync(counts, 0, N_NODES * sizeof(int), stream);

    fuse_weights_kernel<<<1, 256, 0, stream>>>(W_lin, b_lin, att_w, Wa, off8);
    row_kernel<<<2048, 256, 0, stream>>>(x, emb_w, emb_b, Wa, off8, att_b,
                                         hem, s8);
    hist_kernel<<<2048, 256, 0, stream>>>(src, counts);
    scan_kernel<<<1, 1024, 0, stream>>>(counts, rowptr);
    scatter_kernel<<<2048, 256, 0, stream>>>(src, dst, rowptr, counts, sdst);
    node_kernel<<<4096, 256, 0, stream>>>(rowptr, sdst, s8, hem, out);
}

// Round 4
// 636.919 us; speedup vs baseline: 5.5268x; 1.3372x over previous
//
#include <hip/hip_runtime.h>

#define N_NODES 100000
#define E_EDGES 3200000
#define SCAN_BLOCKS 98
#define SCAN_CHUNK 1024  // 98*1024 = 100352 >= N_NODES

// ---------------------------------------------------------------------------
// ws layout (float offsets):
//   hem    [0,        6400000)    N*64   h_em = x @ emb_w + emb_b
//   s8     [6400000,  7200000)    N*8    [s_src+att_b (4) | s_dst (4)] per node
//   Wa     [7200000,  7202048)    256*8  fused W_lin @ [a_src|a_dst]^T
//   off8   [7202048,  7202056)    8      b_lin . a^T
//   counts [7202056,  7302056)    N ints (zeroed by scan3, reused as fill)
//   rowptr [7302056,  7402057)    N+1 ints
//   bsum   [7402064,  7402192)    128 ints (scan partials)
//   boff   [7402192,  7402320)    128 ints (scan block offsets)
//   sdst   [7502064, 10702064)    E ints (dst sorted by src)
// ---------------------------------------------------------------------------

__global__ void fuse_weights_kernel(const float* __restrict__ W_lin,
                                    const float* __restrict__ b_lin,
                                    const float* __restrict__ att_w,
                                    float* __restrict__ Wa,
                                    float* __restrict__ off8) {
    int k = threadIdx.x;  // 0..255, one row of W_lin
    float acc[8];
#pragma unroll
    for (int j = 0; j < 8; ++j) acc[j] = 0.f;
    for (int c = 0; c < 256; ++c) {
        float w = W_lin[k * 256 + c];
#pragma unroll
        for (int l = 0; l < 4; ++l) {
            acc[l]     += w * att_w[l * 512 + c];        // a_src[l][c]
            acc[4 + l] += w * att_w[l * 512 + 256 + c];  // a_dst[l][c]
        }
    }
#pragma unroll
    for (int j = 0; j < 8; ++j) Wa[k * 8 + j] = acc[j];
    if (k < 8) {
        int l = k & 3, part = k >> 2;
        float o = 0.f;
        for (int c = 0; c < 256; ++c)
            o += b_lin[c] * att_w[l * 512 + part * 256 + c];
        off8[k] = o;
    }
}

// 4 rows per wave: hem[row][0..63] for 4 rows (emb_w reuse x4) + s8 rows.
__global__ __launch_bounds__(256) void row_kernel(
    const float* __restrict__ x,
    const float* __restrict__ emb_w, const float* __restrict__ emb_b,
    const float* __restrict__ Wa, const float* __restrict__ off8,
    const float* __restrict__ att_b,
    float* __restrict__ hem, float* __restrict__ s8) {
    __shared__ float4 xs4[4][4][64];  // [wave][row][k/4] = 16 KB
    const int wave = threadIdx.x >> 6, lane = threadIdx.x & 63;
    const int gw = blockIdx.x * 4 + wave, nw = gridDim.x * 4;
    const float eb = emb_b[lane];
    const float* wak = Wa + (lane * 4) * 8;
    for (int g = gw; g < N_NODES / 4; g += nw) {  // 25000 full groups
        const int row0 = g * 4;
        float4 xv[4];
#pragma unroll
        for (int r = 0; r < 4; ++r) {
            xv[r] = *(const float4*)(x + (size_t)(row0 + r) * 256 + lane * 4);
            xs4[wave][r][lane] = xv[r];
        }
#pragma unroll
        for (int r = 0; r < 4; ++r) {
            float sp[8];
#pragma unroll
            for (int j = 0; j < 8; ++j)
                sp[j] = xv[r].x * wak[j] + xv[r].y * wak[8 + j] +
                        xv[r].z * wak[16 + j] + xv[r].w * wak[24 + j];
#pragma unroll
            for (int j = 0; j < 8; ++j) {
                float v = sp[j];
#pragma unroll
                for (int off = 32; off >= 1; off >>= 1) v += __shfl_xor(v, off);
                sp[j] = v;
            }
            if (lane == 0) {
#pragma unroll
                for (int j = 0; j < 8; ++j) {
                    float extra = (j < 4) ? att_b[j] : 0.f;
                    s8[(size_t)(row0 + r) * 8 + j] = sp[j] + off8[j] + extra;
                }
            }
        }
        float ac0 = eb, ac1 = eb, ac2 = eb, ac3 = eb;
        for (int k4 = 0; k4 < 64; ++k4) {
            float4 x0 = xs4[wave][0][k4], x1 = xs4[wave][1][k4];
            float4 x2 = xs4[wave][2][k4], x3 = xs4[wave][3][k4];
            const float* ew = emb_w + (size_t)k4 * 256 + lane;
            float w0 = ew[0], w1 = ew[64], w2 = ew[128], w3 = ew[192];
            ac0 += x0.x * w0 + x0.y * w1 + x0.z * w2 + x0.w * w3;
            ac1 += x1.x * w0 + x1.y * w1 + x1.z * w2 + x1.w * w3;
            ac2 += x2.x * w0 + x2.y * w1 + x2.z * w2 + x2.w * w3;
            ac3 += x3.x * w0 + x3.y * w1 + x3.z * w2 + x3.w * w3;
        }
        hem[(size_t)(row0 + 0) * 64 + lane] = ac0;
        hem[(size_t)(row0 + 1) * 64 + lane] = ac1;
        hem[(size_t)(row0 + 2) * 64 + lane] = ac2;
        hem[(size_t)(row0 + 3) * 64 + lane] = ac3;
    }
}

__global__ __launch_bounds__(256) void hist_kernel(const int* __restrict__ src,
                                                   int* __restrict__ counts) {
    int i = blockIdx.x * blockDim.x + threadIdx.x;
    int stride = gridDim.x * blockDim.x;
    for (int e = i; e < E_EDGES; e += stride)
        atomicAdd(&counts[src[e]], 1);
}

// -------- three-kernel parallel exclusive scan over counts -> rowptr -------
__global__ __launch_bounds__(256) void scan1_kernel(const int* __restrict__ counts,
                                                    int* __restrict__ bsum) {
    __shared__ int red[256];
    const int b = blockIdx.x, t = threadIdx.x;
    const int base = b * SCAN_CHUNK;
    int s = 0;
    for (int i = t; i < SCAN_CHUNK; i += 256) {
        int idx = base + i;
        s += (idx < N_NODES) ? counts[idx] : 0;
    }
    red[t] = s;
    __syncthreads();
    for (int off = 128; off >= 1; off >>= 1) {
        if (t < off) red[t] += red[t + off];
        __syncthreads();
    }
    if (t == 0) bsum[b] = red[0];
}

__global__ __launch_bounds__(128) void scan2_kernel(const int* __restrict__ bsum,
                                                    int* __restrict__ boff,
                                                    int* __restrict__ rowptr) {
    __shared__ int sh[128];
    const int t = threadIdx.x;
    sh[t] = (t < SCAN_BLOCKS) ? bsum[t] : 0;
    __syncthreads();
    for (int off = 1; off < 128; off <<= 1) {
        int v = (t >= off) ? sh[t - off] : 0;
        __syncthreads();
        sh[t] += v;
        __syncthreads();
    }
    if (t < SCAN_BLOCKS) boff[t] = (t == 0) ? 0 : sh[t - 1];
    if (t == 0) rowptr[N_NODES] = E_EDGES;
}

__global__ __launch_bounds__(256) void scan3_kernel(int* __restrict__ counts,
                                                    const int* __restrict__ boff,
                                                    int* __restrict__ rowptr) {
    __shared__ int sh[256];
    const int b = blockIdx.x, t = threadIdx.x;
    const int base = b * SCAN_CHUNK;
    int running = boff[b];
    for (int tile = 0; tile < SCAN_CHUNK; tile += 256) {
        const int idx = base + tile + t;
        const int v = (idx < N_NODES) ? counts[idx] : 0;
        sh[t] = v;
        __syncthreads();
        for (int off = 1; off < 256; off <<= 1) {  // inclusive Hillis-Steele
            int u = (t >= off) ? sh[t - off] : 0;
            __syncthreads();
            sh[t] += u;
            __syncthreads();
        }
        if (idx < N_NODES) {
            rowptr[idx] = running + sh[t] - v;  // exclusive
            counts[idx] = 0;                    // becomes fill[] for scatter
        }
        running += sh[255];
        __syncthreads();  // protect sh[255] read before next tile overwrites
    }
}
// ---------------------------------------------------------------------------

__global__ __launch_bounds__(256) void scatter_kernel(
    const int* __restrict__ src, const int* __restrict__ dst,
    const int* __restrict__ rowptr, int* __restrict__ fill,
    int* __restrict__ sdst) {
    int i = blockIdx.x * blockDim.x + threadIdx.x;
    int stride = gridDim.x * blockDim.x;
    for (int e = i; e < E_EDGES; e += stride) {
        int s = src[e];
        int pos = rowptr[s] + atomicAdd(&fill[s], 1);
        sdst[pos] = dst[e];
    }
}

// One wave per src node. Phase 1: each lane computes the 4 edge-weights for
// ONE edge of the batch -> LDS. Phase 2: broadcast weights, gather hem rows.
__global__ __launch_bounds__(256) void node_kernel(
    const int* __restrict__ rowptr, const int* __restrict__ sdst,
    const float* __restrict__ s8, const float* __restrict__ hem,
    float* __restrict__ out) {
    __shared__ int    wd[4][64];
    __shared__ float4 ww[4][64];
    const int wave = threadIdx.x >> 6, lane = threadIdx.x & 63;
    const int gw = (blockIdx.x * blockDim.x + threadIdx.x) >> 6;
    const int nw = (gridDim.x * blockDim.x) >> 6;
    for (int s = gw; s < N_NODES; s += nw) {
        const int beg = rowptr[s], end = rowptr[s + 1];
        const float4 ssv = *(const float4*)(s8 + (size_t)s * 8);  // +att_b
        float a0 = 0.f, a1 = 0.f, a2 = 0.f, a3 = 0.f;
        float d0 = 0.f, d1 = 0.f, d2 = 0.f, d3 = 0.f;
        for (int base = beg; base < end; base += 64) {
            const int m = min(64, end - base);
            if (lane < m) {
                int dj = sdst[base + lane];
                float4 sd = *(const float4*)(s8 + (size_t)dj * 8 + 4);
                float w0 = __expf(1.f / (1.f + __expf(-(ssv.x + sd.x))));
                float w1 = __expf(1.f / (1.f + __expf(-(ssv.y + sd.y))));
                float w2 = __expf(1.f / (1.f + __expf(-(ssv.z + sd.z))));
                float w3 = __expf(1.f / (1.f + __expf(-(ssv.w + sd.w))));
                wd[wave][lane] = dj;
                ww[wave][lane] = make_float4(w0, w1, w2, w3);
            }
            // producer == consumer wave: DS ops in-order, no block barrier
            int j = 0;
            for (; j + 1 < m; j += 2) {
                int da = wd[wave][j], db = wd[wave][j + 1];
                float4 wa = ww[wave][j], wb = ww[wave][j + 1];
                float ha = hem[(size_t)da * 64 + lane];
                float hb = hem[(size_t)db * 64 + lane];
                a0 += wa.x * ha; a1 += wa.y * ha; a2 += wa.z * ha; a3 += wa.w * ha;
                d0 += wa.x + wb.x; d1 += wa.y + wb.y;
                d2 += wa.z + wb.z; d3 += wa.w + wb.w;
                a0 += wb.x * hb; a1 += wb.y * hb; a2 += wb.z * hb; a3 += wb.w * hb;
            }
            if (j < m) {
                int da = wd[wave][j];
                float4 wa = ww[wave][j];
                float ha = hem[(size_t)da * 64 + lane];
                a0 += wa.x * ha; a1 += wa.y * ha; a2 += wa.z * ha; a3 += wa.w * ha;
                d0 += wa.x; d1 += wa.y; d2 += wa.z; d3 += wa.w;
            }
        }
        float* o = out + (size_t)s * 256;
        o[lane]       = d0 > 0.f ? a0 / d0 : 0.f;
        o[64 + lane]  = d1 > 0.f ? a1 / d1 : 0.f;
        o[128 + lane] = d2 > 0.f ? a2 / d2 : 0.f;
        o[192 + lane] = d3 > 0.f ? a3 / d3 : 0.f;
    }
}

extern "C" void kernel_launch(void* const* d_in, const int* in_sizes, int n_in,
                              void* d_out, int out_size, void* d_ws, size_t ws_size,
                              hipStream_t stream) {
    const float* x     = (const float*)d_in[0];
    const int*   src   = (const int*)d_in[1];
    const int*   dst   = (const int*)d_in[2];
    const float* W_lin = (const float*)d_in[3];
    const float* b_lin = (const float*)d_in[4];
    const float* att_w = (const float*)d_in[5];
    const float* att_b = (const float*)d_in[6];
    const float* emb_w = (const float*)d_in[7];
    const float* emb_b = (const float*)d_in[8];
    float* out = (float*)d_out;
    float* ws  = (float*)d_ws;

    float* hem    = ws;
    float* s8     = ws + 6400000;
    float* Wa     = ws + 7200000;
    float* off8   = ws + 7202048;
    int*   counts = (int*)(ws + 7202056);
    int*   rowptr = (int*)(ws + 7302056);
    int*   bsum   = (int*)(ws + 7402064);
    int*   boff   = (int*)(ws + 7402192);
    int*   sdst   = (int*)(ws + 7502064);

    hipMemsetAsync(counts, 0, N_NODES * sizeof(int), stream);

    fuse_weights_kernel<<<1, 256, 0, stream>>>(W_lin, b_lin, att_w, Wa, off8);
    row_kernel<<<2048, 256, 0, stream>>>(x, emb_w, emb_b, Wa, off8, att_b,
                                         hem, s8);
    hist_kernel<<<2048, 256, 0, stream>>>(src, counts);
    scan1_kernel<<<SCAN_BLOCKS, 256, 0, stream>>>(counts, bsum);
    scan2_kernel<<<1, 128, 0, stream>>>(bsum, boff, rowptr);
    scan3_kernel<<<SCAN_BLOCKS, 256, 0, stream>>>(counts, boff, rowptr);
    scatter_kernel<<<2048, 256, 0, stream>>>(src, dst, rowptr, counts, sdst);
    node_kernel<<<4096, 256, 0, stream>>>(rowptr, sdst, s8, hem, out);
}